// Round 6
// baseline (126.449 us; speedup 1.0000x reference)
//
#include <hip/hip_runtime.h>
#include <math.h>

// TeacherMLP fused forward.
// R16 = R15's packed-Pade structure with ALL inline asm removed from
// mlp_kernel: v2f (ext_vector_type(2) float) C arithmetic +
// __builtin_elementwise_fma, broadcasts as explicit splats. Rationale:
// failures R9/R11/R13/R15 (absmax ~50-60) all share inline-asm-defined v2f
// values under register pressure (64-VGPR cap or deep ND chains); passing
// builds (R10/R12 shallow chains, R14 no asm) don't. Asm-opaque 64-bit
// temporaries that spill appear to corrupt; compiler-known vectors cannot.
// gfx90a+ has V_PK_{ADD,MUL,FMA}_F32 selection for <2 x float> IR, so this
// may pack without asm:
//   packed    -> mlp 62 -> 28-38us (issue floor ~17us + stall floor)
//   scalarized-> mlp ~62us, R14 parity (no regression; proves asm needed)
// Either way it should PASS (math identical to twice-proven Pade(5,4)).

typedef float v2f __attribute__((ext_vector_type(2)));

#define HCLAMP 12.0f
#define INV2PI 0.15915494309189535f
#define SCW    2.885390081777927f    /* only weff's tanh-atom uses exp2 */

__device__ __forceinline__ float fast_rcp(float x)  { return __builtin_amdgcn_rcpf(x); }
__device__ __forceinline__ float fast_exp2(float x) { return __builtin_amdgcn_exp2f(x); }
__device__ __forceinline__ v2f pk2(float a, float b) { v2f r; r.x = a; r.y = b; return r; }
__device__ __forceinline__ v2f splat2(float f) { v2f r; r.x = f; r.y = f; return r; }
__device__ __forceinline__ v2f vfma(v2f a, v2f b, v2f c) {
    return __builtin_elementwise_fma(a, b, c);
}

__global__ void weff_kernel(const float* __restrict__ W0, const int* __restrict__ I0,
                            const float* __restrict__ W1, const int* __restrict__ I1,
                            const float* __restrict__ W2, const int* __restrict__ I2,
                            float* __restrict__ ws) {
    int tid = blockIdx.x * blockDim.x + threadIdx.x;   // 0 .. 163839
    const float* W; const int* I; float* out; int outd; int e;
    if (tid < 65536)        { W = W0; I = I0; out = ws;          outd = 256; e = tid; }
    else if (tid < 131072)  { W = W1; I = I1; out = ws + 65536;  outd = 256; e = tid - 65536; }
    else if (tid < 163840)  { W = W2; I = I2; out = ws + 131072; outd = 128; e = tid - 131072; }
    else return;
    int o = e >> 8;       // out index (in-dim always 256)
    int i = e & 255;      // in index
    float w = W[e];       // coalesced (e = o*256 + i)
    int idx = I[e];
    // branchless atoms: [id, sin, tanh, square]
    float sn = __builtin_amdgcn_sinf(w * INV2PI);
    float th = 1.0f - 2.0f * fast_rcp(fast_exp2(w * SCW) + 1.0f);
    float sq = w * w;
    float v = (idx == 1) ? sn : (idx == 2) ? th : (idx == 3) ? sq : w;
    // packed store: [i/4][o][i%4] -> main loop reads float4 of 4 K-values
    out[(i >> 2) * (outd * 4) + o * 4 + (i & 3)] = v;
}

// ---- packed Pade(5,4) tanh as (num, den), pure C vector ops:
//      tanh z = z(945+105t+t^2)/(945+420t+15t^2), t=z^2  (proven in R14)
struct ND { v2f n, d; };
__device__ __forceinline__ ND pade1(v2f z) {
    const v2f c105 = splat2(105.0f), c945 = splat2(945.0f);
    const v2f c420 = splat2(420.0f), c15  = splat2(15.0f);
    v2f t = z * z;
    ND r;
    r.n = z * vfma(t, t + c105, c945);       // z(t^2+105t+945)
    r.d = vfma(t, vfma(t, c15, c420), c945); // 15t^2+420t+945
    return r;
}
__device__ __forceinline__ ND nd_merge(ND a, ND b) {
    ND r;
    r.n = vfma(a.n, b.d, b.n * a.d);
    r.d = a.d * b.d;
    return r;
}
// 4 k-terms (one float4 of weights) for one packed row-pair -> one ND.
__device__ __forceinline__ ND tree4(float4 pa, float4 pb, float4 w) {
    v2f h0 = pk2(pa.x, pa.y), h1 = pk2(pa.z, pa.w);
    v2f h2 = pk2(pb.x, pb.y), h3 = pk2(pb.z, pb.w);
    ND r0 = pade1(h0 * splat2(w.x));
    ND r1 = pade1(h1 * splat2(w.y));
    ND r2 = pade1(h2 * splat2(w.z));
    ND r3 = pade1(h3 * splat2(w.w));
    return nd_merge(nd_merge(r0, r1), nd_merge(r2, r3));
}
// merge two 4-trees (8 tanh terms, one row-pair) with ONE rcp per row.
__device__ __forceinline__ v2f sig8_acc(ND a, ND b, v2f acc) {
    v2f num = vfma(b.n, a.d, a.n * b.d);
    v2f den = a.d * b.d;
    v2f rd;  rd.x = fast_rcp(den.x); rd.y = fast_rcp(den.y);
    return vfma(num, rd, acc);
}

__global__ __launch_bounds__(1024, 4) void mlp_kernel(
    const float* __restrict__ x,  const float* __restrict__ b0,
    const float* __restrict__ b1, const float* __restrict__ b2,
    const float* __restrict__ ws, float* __restrict__ out) {
    const float4* We0 = (const float4*)ws;             // [64][256] packed [ic][o][4]
    const float4* We1 = (const float4*)(ws + 65536);   // [64][256]
    const float4* We2 = (const float4*)(ws + 131072);  // [64][128]

    __shared__ __align__(16) v2f hA0[256];      // pair0: rows (row0, row0+1)
    __shared__ __align__(16) v2f hA1[256];      // pair1: rows (row0+2, row0+3)
    __shared__ __align__(16) v2f hB0[256];
    __shared__ __align__(16) v2f hB1[256];
    __shared__ __align__(16) v2f partA[1024];   // split-K partials, pair 0
    __shared__ __align__(16) v2f partB[1024];   // pair 1

    const int t = threadIdx.x;     // 0..1023
    const int g = t >> 8;          // K-group 0..3 (wave-uniform)
    const int o = t & 255;         // neuron
    const int p = g >> 1;          // pair select (staging/epilogue role)
    const int l = g & 1;           // lane within pair
    const int row0 = blockIdx.x * 4;

    // stage 4 input rows: thread (g,o) stages row row0+2p+l, column o.
    {
        float xv = x[(row0 + 2 * p + l) * 256 + o];
        xv = fminf(fmaxf(xv, -HCLAMP), HCLAMP);
        ((float*)((p ? hA1 : hA0) + o))[l] = xv;
    }
    __syncthreads();

    // ---------------- layer 0: hA* -> hB* ----------------
    {
        const float bias = b0[o];
        v2f acc0 = splat2(0.f), acc1 = splat2(0.f);
#pragma unroll 1
        for (int icc = 0; icc < 16; icc += 2) {
            int ic = g * 16 + icc;
            float4 w0 = We0[ic * 256 + o];
            float4 w1 = We0[(ic + 1) * 256 + o];
            const float4* hp0 = (const float4*)(hA0 + ic * 4);
            const float4* hp1 = (const float4*)(hA1 + ic * 4);
            ND r0 = tree4(hp0[0], hp0[1], w0);
            ND r1 = tree4(hp0[2], hp0[3], w1);
            acc0 = sig8_acc(r0, r1, acc0);
            ND r2 = tree4(hp1[0], hp1[1], w0);   // independent chain
            ND r3 = tree4(hp1[2], hp1[3], w1);
            acc1 = sig8_acc(r2, r3, acc1);
        }
        partA[g * 256 + o] = acc0;
        partB[g * 256 + o] = acc1;
        __syncthreads();
        const v2f* prt = p ? partB : partA;
        float s = ((const float*)(prt + o))[l]
                + ((const float*)(prt + 256 + o))[l]
                + ((const float*)(prt + 512 + o))[l]
                + ((const float*)(prt + 768 + o))[l];
        float h = s + bias;                      // s = sum of 256 tanh terms
        h = fminf(fmaxf(h, -HCLAMP), HCLAMP);
        ((float*)((p ? hB1 : hB0) + o))[l] = h;
        __syncthreads();
    }

    // ---------------- layer 1: hB* -> (hA0, hB1) ----------------
    {
        const float bias = b1[o];
        v2f acc0 = splat2(0.f), acc1 = splat2(0.f);
#pragma unroll 1
        for (int icc = 0; icc < 16; icc += 2) {
            int ic = g * 16 + icc;
            float4 w0 = We1[ic * 256 + o];
            float4 w1 = We1[(ic + 1) * 256 + o];
            const float4* hp0 = (const float4*)(hB0 + ic * 4);
            const float4* hp1 = (const float4*)(hB1 + ic * 4);
            ND r0 = tree4(hp0[0], hp0[1], w0);
            ND r1 = tree4(hp0[2], hp0[3], w1);
            acc0 = sig8_acc(r0, r1, acc0);
            ND r2 = tree4(hp1[0], hp1[1], w0);
            ND r3 = tree4(hp1[2], hp1[3], w1);
            acc1 = sig8_acc(r2, r3, acc1);
        }
        partA[g * 256 + o] = acc0;
        partB[g * 256 + o] = acc1;
        __syncthreads();
        const v2f* prt = p ? partB : partA;
        float s = ((const float*)(prt + o))[l]
                + ((const float*)(prt + 256 + o))[l]
                + ((const float*)(prt + 512 + o))[l]
                + ((const float*)(prt + 768 + o))[l];
        float h = s + bias;
        h = fminf(fmaxf(h, -HCLAMP), HCLAMP);
        // pair0 -> hA0, pair1 -> hB1 (hB1's inner-loop reads completed before
        // the barrier above; hA1 stays untouched to avoid any WAR surprise).
        ((float*)((p ? hB1 : hA0) + o))[l] = h;
        __syncthreads();
    }

    // ---------------- layer 2: (hA0 pair0, hB1 pair1) -> out ----------------
    {
        const int o2 = t & 127;
        const int q  = t >> 7;     // K-eighth 0..7
        v2f acc0 = splat2(0.f), acc1 = splat2(0.f);
#pragma unroll 4
        for (int icc = 0; icc < 8; icc++) {
            int ic = q * 8 + icc;
            float4 w = We2[ic * 128 + o2];
            const float4* hp0 = (const float4*)(hA0 + ic * 4);
            const float4* hp1 = (const float4*)(hB1 + ic * 4);
            float4 pa = hp0[0], pb = hp0[1];
            float4 qa = hp1[0], qb = hp1[1];
            acc0 = vfma(pk2(pa.x, pa.y), splat2(w.x), acc0);
            acc0 = vfma(pk2(pa.z, pa.w), splat2(w.y), acc0);
            acc0 = vfma(pk2(pb.x, pb.y), splat2(w.z), acc0);
            acc0 = vfma(pk2(pb.z, pb.w), splat2(w.w), acc0);
            acc1 = vfma(pk2(qa.x, qa.y), splat2(w.x), acc1);
            acc1 = vfma(pk2(qa.z, qa.w), splat2(w.y), acc1);
            acc1 = vfma(pk2(qb.x, qb.y), splat2(w.z), acc1);
            acc1 = vfma(pk2(qb.z, qb.w), splat2(w.w), acc1);
        }
        partA[q * 128 + o2] = acc0;
        partB[q * 128 + o2] = acc1;
        __syncthreads();
        // 512 outputs (4 rows x 128), one per thread in the first half-block.
        if (t < 512) {
            const int r  = t >> 7;        // 0..3 -> row row0 + r
            const int oo = t & 127;
            const v2f* prt = (r & 2) ? partB : partA;
            const int  ln  = r & 1;
            float s = 0.0f;
#pragma unroll
            for (int q2 = 0; q2 < 8; q2++)
                s += ((const float*)(prt + q2 * 128 + oo))[ln];
            out[(row0 + r) * 128 + oo] = s + b2[oo];
        }
    }
}

extern "C" void kernel_launch(void* const* d_in, const int* in_sizes, int n_in,
                              void* d_out, int out_size, void* d_ws, size_t ws_size,
                              hipStream_t stream) {
    const float* x  = (const float*)d_in[0];
    const float* W0 = (const float*)d_in[1];
    const float* b0 = (const float*)d_in[2];
    const int*   I0 = (const int*)  d_in[3];
    const float* W1 = (const float*)d_in[4];
    const float* b1 = (const float*)d_in[5];
    const int*   I1 = (const int*)  d_in[6];
    const float* W2 = (const float*)d_in[7];
    const float* b2 = (const float*)d_in[8];
    const int*   I2 = (const int*)  d_in[9];
    float* ws  = (float*)d_ws;    // 163840 floats = 655360 B
    float* out = (float*)d_out;

    weff_kernel<<<640, 256, 0, stream>>>(W0, I0, W1, I1, W2, I2, ws);
    mlp_kernel<<<512, 1024, 0, stream>>>(x, b0, b1, b2, ws, out);
}